// Round 9
// baseline (1907.950 us; speedup 1.0000x reference)
//
#include <hip/hip_runtime.h>
#include <math.h>

#define LN_EPS 1e-5f

typedef short s8v __attribute__((ext_vector_type(8)));
typedef float f4v __attribute__((ext_vector_type(4)));

__device__ __forceinline__ short f2bf(float x) {
  union { float f; unsigned u; } v; v.f = x;
  const unsigned r = v.u + 0x7fffu + ((v.u >> 16) & 1u);
  return (short)(r >> 16);
}
__device__ __forceinline__ float bf2f(short s) {
  union { unsigned u; float f; } v;
  v.u = ((unsigned)(unsigned short)s) << 16;
  return v.f;
}

__device__ __forceinline__ void gld16(const void* g, void* l) {
  __builtin_amdgcn_global_load_lds(
      (const __attribute__((address_space(1))) void*)g,
      (__attribute__((address_space(3))) void*)l, 16, 0, 0);
}

enum { EP_SPLIT = 0, EP_SPLIT_T, EP_SIG, EP_RES, EP_BIAS, EP_ACC, EP_ACCGELU,
       EP_GELUB };

// Split-bf16 NT GEMM: C = A * B^T, A[M][K], B[N][K], both given as hi/lo bf16.
// 3-term MFMA (hi*hi + hi*lo + lo*hi) ~= fp32 precision. BM=128, BN=64*WC,
// BK=64, 2*WC waves (wave-tile 64x64 of 16x16x32 frags). XOR(row&7) chunk16
// bank-swizzle on the global SOURCE during global_load_lds (linear LDS dest)
// and the same involution on ds_read -> conflict-free.
//
// 1D grid, XCD-bijective chunking (nwg%8==0 always), decoded panel-major with
// two batch dims: l -> pn (fastest), pm, bz (inner batch, e.g. B=8), zz (cross
// block within launch). Same-A-panel blocks stay consecutive in one XCD chunk.
template <int EP, int WC>
__global__ __launch_bounds__(128 * WC) void gemmk(
    const short* __restrict__ Ah, const short* __restrict__ Al,
    const short* __restrict__ Bh, const short* __restrict__ Bl,
    short* __restrict__ Ch, short* __restrict__ Cl, float* __restrict__ Cf,
    const float* __restrict__ bias, const short* __restrict__ resH,
    const short* __restrict__ resL, float* __restrict__ out2, int pnCnt,
    int pmCnt, int bCnt, int lda, int ldb, int ldc, int K, long sA, long sB,
    long sC, long sAz, long sBz, long sCz, long sRz, int biasZ, float scale) {
  constexpr int BM = 128, BN = 64 * WC, T = 128 * WC;
  constexpr int RA = (BM * 128) / (T * 16);
  constexpr int RB = (BN * 128) / (T * 16);
  __shared__ short lds[(2 * BM + 2 * BN) * 64];
  short* AsH = lds;
  short* AsL = lds + BM * 64;
  short* BsH = lds + 2 * BM * 64;
  short* BsL = lds + 2 * BM * 64 + BN * 64;

  const int tid = threadIdx.x;
  const int lane = tid & 63;
  const int wave = tid >> 6;
  const int wr = wave / WC;
  const int wc = wave % WC;
  const int half = lane >> 4;
  const int l15 = lane & 15;

  // XCD-chunked panel-major decode
  const int chunk = gridDim.x >> 3;
  const int l = ((int)blockIdx.x & 7) * chunk + ((int)blockIdx.x >> 3);
  const int pn = l % pnCnt;
  const int t1 = l / pnCnt;
  const int pm = t1 % pmCnt;
  const int t2 = t1 / pmCnt;
  const int bz = t2 % bCnt;
  const int zz = t2 / bCnt;
  const int bm = pm * BM;
  const int bn = pn * BN;

  Ah += bz * sA + zz * sAz;
  Al += bz * sA + zz * sAz;
  Bh += bz * sB + zz * sBz;
  Bl += bz * sB + zz * sBz;
  const long cOff = bz * sC + (long)zz * sCz;

  f4v acc[4][4];
#pragma unroll
  for (int i = 0; i < 4; ++i)
#pragma unroll
    for (int j = 0; j < 4; ++j)
#pragma unroll
      for (int r = 0; r < 4; ++r) acc[i][j][r] = 0.f;

  for (int k0 = 0; k0 < K; k0 += 64) {
    __syncthreads();  // protect LDS from previous iteration's readers
#pragma unroll
    for (int t = 0; t < RA; ++t) {
      const int off = (t * T + tid) * 16;
      const int row = off >> 7;
      const int ke = ((((off >> 4) & 7) ^ (row & 7)) << 3);
      const long ga = (long)(bm + row) * lda + k0 + ke;
      gld16(Ah + ga, (char*)AsH + off);
      gld16(Al + ga, (char*)AsL + off);
    }
#pragma unroll
    for (int t = 0; t < RB; ++t) {
      const int off = (t * T + tid) * 16;
      const int row = off >> 7;
      const int ke = ((((off >> 4) & 7) ^ (row & 7)) << 3);
      const long gb = (long)(bn + row) * ldb + k0 + ke;
      gld16(Bh + gb, (char*)BsH + off);
      gld16(Bl + gb, (char*)BsL + off);
    }
    __syncthreads();

#pragma unroll
    for (int s = 0; s < 2; ++s) {
      s8v ah[4], al[4], bh[4], bl[4];
#pragma unroll
      for (int i = 0; i < 4; ++i) {
        const int r = wr * 64 + i * 16 + l15;
        const int ad = r * 64 + ((((s << 2) + half) ^ (r & 7)) << 3);
        ah[i] = *(const s8v*)&AsH[ad];
        al[i] = *(const s8v*)&AsL[ad];
      }
#pragma unroll
      for (int j = 0; j < 4; ++j) {
        const int c = wc * 64 + j * 16 + l15;
        const int bd = c * 64 + ((((s << 2) + half) ^ (c & 7)) << 3);
        bh[j] = *(const s8v*)&BsH[bd];
        bl[j] = *(const s8v*)&BsL[bd];
      }
#pragma unroll
      for (int i = 0; i < 4; ++i)
#pragma unroll
        for (int j = 0; j < 4; ++j) {
          acc[i][j] = __builtin_amdgcn_mfma_f32_16x16x32_bf16(ah[i], bh[j],
                                                              acc[i][j], 0, 0, 0);
          acc[i][j] = __builtin_amdgcn_mfma_f32_16x16x32_bf16(ah[i], bl[j],
                                                              acc[i][j], 0, 0, 0);
          acc[i][j] = __builtin_amdgcn_mfma_f32_16x16x32_bf16(al[i], bh[j],
                                                              acc[i][j], 0, 0, 0);
        }
    }
  }

  // Epilogue. D frag: col = lane&15, row = (lane>>4)*4 + reg (m89-verified).
#pragma unroll
  for (int i = 0; i < 4; ++i) {
#pragma unroll
    for (int r = 0; r < 4; ++r) {
      const int row = bm + wr * 64 + i * 16 + half * 4 + r;
#pragma unroll
      for (int j = 0; j < 4; ++j) {
        const int col = bn + wc * 64 + j * 16 + l15;
        float x = acc[i][j][r];
        if (EP == EP_SPLIT) {
          const long idx = cOff + (long)row * ldc + col;
          const short h = f2bf(x);
          Ch[idx] = h;
          Cl[idx] = f2bf(x - bf2f(h));
        } else if (EP == EP_SPLIT_T) {
          // v-projection: vt[b][col][tok]; row = b*1024+tok (bCnt==1)
          const long idx =
              cOff + ((long)(row >> 10) * 576 + col) * 1024 + (row & 1023);
          const short h = f2bf(x);
          Ch[idx] = h;
          Cl[idx] = f2bf(x - bf2f(h));
        } else if (EP == EP_SIG) {
          x = 1.f / (1.f + expf(-x * scale));
          const long idx = cOff + (long)row * ldc + col;
          const short h = f2bf(x);
          Ch[idx] = h;
          Cl[idx] = f2bf(x - bf2f(h));
        } else if (EP == EP_RES) {
          const long idx = cOff + (long)row * ldc + col;
          const long ridx = zz * sRz + (long)row * ldc + col;
          Cf[idx] = x + bias[zz * biasZ + col] + bf2f(resH[ridx]) +
                    bf2f(resL[ridx]);
        } else if (EP == EP_BIAS) {
          const long idx = cOff + (long)row * ldc + col;
          Cf[idx] = x + bias[zz * biasZ + col];
        } else if (EP == EP_ACC) {
          const long idx = cOff + (long)row * ldc + col;
          Cf[idx] += x;
        } else if (EP == EP_ACCGELU) {
          const long idx = cOff + (long)row * ldc + col;
          const float sum = Cf[idx] + x;
          out2[idx] = 0.5f * sum * (1.f + erff(sum * 0.70710678118654752f));
        } else if (EP == EP_GELUB) {
          const long idx = cOff + (long)row * ldc + col;
          const float sum = x + bias[zz * biasZ + col];
          out2[idx] = 0.5f * sum * (1.f + erff(sum * 0.70710678118654752f));
        }
      }
    }
  }
}

struct LnSrc {
  const float* p[6];
};

// Batched LayerNorm over C=576. grid = 8192*G; zz = bid>>13. Writes hi/lo
// split at oh/ol + zz*oz + row*ldo + t (oz/ldo make both slab and concat
// layouts expressible).
__global__ __launch_bounds__(576) void ln576b(LnSrc srcs,
                                              const float* __restrict__ g,
                                              const float* __restrict__ b,
                                              short* __restrict__ oh,
                                              short* __restrict__ ol, long oz,
                                              int ldo) {
  __shared__ float red[2][9];
  __shared__ float mu_s, rs_s;
  const int zz = blockIdx.x >> 13;
  const long row = blockIdx.x & 8191;
  const int t = threadIdx.x;
  const float v = srcs.p[zz][row * 576 + t];
  float s = v, s2 = v * v;
#pragma unroll
  for (int off = 32; off > 0; off >>= 1) {
    s += __shfl_xor(s, off);
    s2 += __shfl_xor(s2, off);
  }
  if ((t & 63) == 0) {
    red[0][t >> 6] = s;
    red[1][t >> 6] = s2;
  }
  __syncthreads();
  if (t == 0) {
    float a = 0.f, a2 = 0.f;
#pragma unroll
    for (int i = 0; i < 9; ++i) {
      a += red[0][i];
      a2 += red[1][i];
    }
    const float mu = a * (1.f / 576.f);
    mu_s = mu;
    rs_s = rsqrtf(a2 * (1.f / 576.f) - mu * mu + LN_EPS);
  }
  __syncthreads();
  const float y = (v - mu_s) * rs_s * g[zz * 576 + t] + b[zz * 576 + t];
  const short h = f2bf(y);
  const long idx = zz * oz + row * ldo + t;
  oh[idx] = h;
  ol[idx] = f2bf(y - bf2f(h));
}

__global__ __launch_bounds__(256) void splitk(const float* __restrict__ in,
                                              short* __restrict__ oh,
                                              short* __restrict__ ol, long n) {
  long i = (long)blockIdx.x * blockDim.x + threadIdx.x;
  const long stride = (long)gridDim.x * blockDim.x;
  for (; i < n; i += stride) {
    const float x = in[i];
    const short h = f2bf(x);
    oh[i] = h;
    ol[i] = f2bf(x - bf2f(h));
  }
}

extern "C" void kernel_launch(void* const* d_in, const int* in_sizes, int n_in,
                              void* d_out, int out_size, void* d_ws,
                              size_t ws_size, hipStream_t stream) {
  const float* img = (const float*)d_in[0];
  const float* aolp = (const float*)d_in[1];
  const float* dolp = (const float*)d_in[2];
  const float* lnx_g = (const float*)d_in[3];
  const float* lnx_b = (const float*)d_in[4];
  const float* lny_g = (const float*)d_in[5];
  const float* lny_b = (const float*)d_in[6];
  const float* lnz_g = (const float*)d_in[7];
  const float* lnz_b = (const float*)d_in[8];
  const float* Wq = (const float*)d_in[9];
  const float* Wk = (const float*)d_in[10];
  const float* Wv = (const float*)d_in[11];
  const float* Wp = (const float*)d_in[12];
  const float* bp = (const float*)d_in[13];
  const float* Wf = (const float*)d_in[14];
  const float* bf = (const float*)d_in[15];
  float* out = (float*)d_out;

  const long S = 8L * 1024 * 576;    // 4,718,592
  const long W = 6L * 576 * 576;     // 1,990,656 (== 576*3456)
  const long AT = 16L * 1024 * 1024; // attn slot per z (hi 8M + lo 8M shorts)

  // choose batching factor G by ws_size (constant across calls -> graph-safe)
  const long fixed = 10 * (W * 2 + 256) + 4 * (8192L * 3456 * 2 + 256);
  const long perz = 10 * (S * 2 + 256) + (AT * 2 + 256);
  int G = 1;
  bool mega = true;
  if ((long)ws_size >= fixed + 6 * perz) G = 6;
  else if ((long)ws_size >= fixed + 3 * perz) G = 3;
  else if ((long)ws_size >= fixed + 2 * perz) G = 2;
  else if ((long)ws_size >= fixed + 1 * perz) G = 1;
  else { G = 1; mega = false; }  // fallback: accumulate path (~187MB)

  char* p = (char*)d_ws;
  auto alloc = [&](long bytes) {
    char* r = p;
    p += (bytes + 255) & ~255L;
    return r;
  };
  short* wq_h = (short*)alloc(W * 2); short* wq_l = (short*)alloc(W * 2);
  short* wk_h = (short*)alloc(W * 2); short* wk_l = (short*)alloc(W * 2);
  short* wv_h = (short*)alloc(W * 2); short* wv_l = (short*)alloc(W * 2);
  short* wp_h = (short*)alloc(W * 2); short* wp_l = (short*)alloc(W * 2);
  short* wf_h = (short*)alloc(W * 2); short* wf_l = (short*)alloc(W * 2);
  short* zn_h = nullptr; short* zn_l = nullptr; float* fused = nullptr;
  if (mega) {
    zn_h = (short*)alloc(8192L * 3456 * 2);
    zn_l = (short*)alloc(8192L * 3456 * 2);
  }
  short* xn_h = (short*)alloc(G * S * 2); short* xn_l = (short*)alloc(G * S * 2);
  short* yn_h = (short*)alloc(G * S * 2); short* yn_l = (short*)alloc(G * S * 2);
  short* q_h = (short*)alloc(G * S * 2);  short* q_l = (short*)alloc(G * S * 2);
  short* k_h = (short*)alloc(G * S * 2);  short* k_l = (short*)alloc(G * S * 2);
  short* vt_h = (short*)alloc(G * S * 2); short* vt_l = (short*)alloc(G * S * 2);
  short* attnA = (short*)alloc(G * AT * 2);  // per z: [hi 8M][lo 8M]
  short* attn_h = attnA;
  short* attn_l = attnA + 8388608;
  float* t_f32 = (float*)attnA;  // aliases attn per z (z-stride 8388608 floats)
  if (!mega) fused = (float*)alloc(S * 4);

  splitk<<<1024, 256, 0, stream>>>(Wq, wq_h, wq_l, W);
  splitk<<<1024, 256, 0, stream>>>(Wk, wk_h, wk_l, W);
  splitk<<<1024, 256, 0, stream>>>(Wv, wv_h, wv_l, W);
  splitk<<<1024, 256, 0, stream>>>(Wp, wp_h, wp_l, W);
  splitk<<<1024, 256, 0, stream>>>(Wf, wf_h, wf_l, W);

  const float* src[3] = {img, aolp, dolp};
  const int xi[6] = {0, 0, 1, 1, 2, 2};
  const int yi[6] = {1, 2, 0, 2, 0, 1};
  const float scale = 1.f / 24.f;
  const long WZ = 576L * 576;  // weight z-stride
  const long TZ = 8388608;     // t_f32 z-stride (floats)

  for (int g0 = 0; g0 < 6; g0 += G) {
    LnSrc sx, sy, st;
    for (int zz = 0; zz < G; ++zz) {
      sx.p[zz] = src[xi[g0 + zz]];
      sy.p[zz] = src[yi[g0 + zz]];
      st.p[zz] = t_f32 + zz * TZ;
    }
    ln576b<<<8192 * G, 576, 0, stream>>>(sx, lnx_g + g0 * 576, lnx_b + g0 * 576,
                                         xn_h, xn_l, S, 576);
    ln576b<<<8192 * G, 576, 0, stream>>>(sy, lny_g + g0 * 576, lny_b + g0 * 576,
                                         yn_h, yn_l, S, 576);
    // q = LN(y)@Wq^T, k = LN(x)@Wk^T, vt = (LN(x)@Wv^T)^T   (batched over zz)
    gemmk<EP_SPLIT, 1><<<576 * G, 128, 0, stream>>>(
        yn_h, yn_l, wq_h + g0 * WZ, wq_l + g0 * WZ, q_h, q_l, nullptr, nullptr,
        nullptr, nullptr, nullptr, 9, 64, 1, 576, 576, 576, 576, 0, 0, 0, S, WZ,
        S, 0, 0, 0.f);
    gemmk<EP_SPLIT, 1><<<576 * G, 128, 0, stream>>>(
        xn_h, xn_l, wk_h + g0 * WZ, wk_l + g0 * WZ, k_h, k_l, nullptr, nullptr,
        nullptr, nullptr, nullptr, 9, 64, 1, 576, 576, 576, 576, 0, 0, 0, S, WZ,
        S, 0, 0, 0.f);
    gemmk<EP_SPLIT_T, 1><<<576 * G, 128, 0, stream>>>(
        xn_h, xn_l, wv_h + g0 * WZ, wv_l + g0 * WZ, vt_h, vt_l, nullptr,
        nullptr, nullptr, nullptr, nullptr, 9, 64, 1, 576, 576, 0, 576, 0, 0, 0,
        S, WZ, S, 0, 0, 0.f);
    // attn = sigmoid(q@k^T * scale), per batch b and zz
    gemmk<EP_SIG, 2><<<512 * G, 256, 0, stream>>>(
        q_h, q_l, k_h, k_l, attn_h, attn_l, nullptr, nullptr, nullptr, nullptr,
        nullptr, 8, 8, 8, 576, 576, 1024, 576, 1024L * 576, 1024L * 576,
        1024L * 1024, S, S, AT, 0, 0, scale);
    // o = attn @ vt^T (into yn)
    gemmk<EP_SPLIT, 1><<<576 * G, 128, 0, stream>>>(
        attn_h, attn_l, vt_h, vt_l, yn_h, yn_l, nullptr, nullptr, nullptr,
        nullptr, nullptr, 9, 8, 8, 1024, 1024, 576, 1024, 1024L * 1024,
        576L * 1024, 1024L * 576, AT, S, S, 0, 0, 0.f);
    // t = o @ Wp^T + bp + xn   (fp32, into attn-aliased t buffer)
    gemmk<EP_RES, 1><<<576 * G, 128, 0, stream>>>(
        yn_h, yn_l, wp_h + g0 * WZ, wp_l + g0 * WZ, nullptr, nullptr, t_f32,
        bp + g0 * 576, xn_h, xn_l, nullptr, 9, 64, 1, 576, 576, 576, 576, 0, 0,
        0, S, WZ, TZ, S, 576, 0.f);
    if (mega) {
      // zn -> concat buffer [8192][3456] at col (g0+zz)*576
      ln576b<<<8192 * G, 576, 0, stream>>>(st, lnz_g + g0 * 576,
                                           lnz_b + g0 * 576, zn_h + g0 * 576,
                                           zn_l + g0 * 576, 576L, 3456);
    } else {
      const int z = g0;  // G==1
      ln576b<<<8192, 576, 0, stream>>>(st, lnz_g + z * 576, lnz_b + z * 576,
                                       q_h, q_l, 0, 576);
      if (z == 0)
        gemmk<EP_BIAS, 1><<<576, 128, 0, stream>>>(
            q_h, q_l, wf_h + z * 576, wf_l + z * 576, nullptr, nullptr, fused,
            bf, nullptr, nullptr, nullptr, 9, 64, 1, 576, 3456, 576, 576, 0, 0,
            0, 0, 0, 0, 0, 0, 0.f);
      else if (z < 5)
        gemmk<EP_ACC, 1><<<576, 128, 0, stream>>>(
            q_h, q_l, wf_h + z * 576, wf_l + z * 576, nullptr, nullptr, fused,
            nullptr, nullptr, nullptr, nullptr, 9, 64, 1, 576, 3456, 576, 576,
            0, 0, 0, 0, 0, 0, 0, 0, 0.f);
      else
        gemmk<EP_ACCGELU, 1><<<576, 128, 0, stream>>>(
            q_h, q_l, wf_h + z * 576, wf_l + z * 576, nullptr, nullptr, fused,
            nullptr, nullptr, nullptr, out, 9, 64, 1, 576, 3456, 576, 576, 0, 0,
            0, 0, 0, 0, 0, 0, 0.f);
    }
  }
  if (mega) {
    // out = gelu(concat @ Wf^T + bf): M=8192, N=576, K=3456 (54 K-iters)
    gemmk<EP_GELUB, 1><<<576, 128, 0, stream>>>(
        zn_h, zn_l, wf_h, wf_l, nullptr, nullptr, nullptr, bf, nullptr, nullptr,
        out, 9, 64, 1, 3456, 3456, 576, 3456, 0, 0, 0, 0, 0, 0, 0, 0, 0.f);
  }
}